// Round 2
// baseline (17768.474 us; speedup 1.0000x reference)
//
#include <hip/hip_runtime.h>

// ---------------------------------------------------------------------------
// Persistent cooperative 2-layer LSTM encoder/decoder for MI355X (gfx950).
//   - 512 blocks x 256 thr (2 blocks/CU), co-resident via cooperative launch
//     (fallback: plain launch; occupancy guaranteed by launch_bounds).
//   - Weights live in VGPRs as bf16 MFMA B-fragments (loaded once).
//   - 4 waves/block split K (strided ksteps) -> staged A chunks read ONCE.
//   - bf16 partial-gate exchange in LDS, fp32 cell update, fp32 c in regs.
//   - h double-buffered (parity) in ws; agent-scope flag-counter dataflow.
//   - All spin-waits bounded (~0.5s) so bugs -> fast wrong answer, not hang.
// ---------------------------------------------------------------------------

typedef __attribute__((ext_vector_type(8))) short bf16x8;
typedef __attribute__((ext_vector_type(16))) float f32x16;

#define MFMA32(a, b, c) __builtin_amdgcn_mfma_f32_32x32x16_bf16((a), (b), (c), 0, 0, 0)
#define DEV static __device__ __forceinline__

constexpr int kSeq = 128;          // encoder steps
constexpr int kT = 175;            // total lstm steps (128 + 47)
constexpr int kBT = 64;            // batch rows per block
constexpr int kProd = 32;          // producer blocks per (layer, bc)
constexpr int kHP = 1024;          // hbuf row pitch: cols 0-511 h0, 512-1023 h1

// workspace layout (bytes)
constexpr size_t kWsHbuf = 0;                              // [2][512][1024] bf16
constexpr size_t kWsYacc = 2ull * 512 * kHP * 2;           // [2][512][8] f32
constexpr size_t kWsCnt0 = kWsYacc + 2ull * 512 * 8 * 4;   // [176][8] u32
constexpr size_t kWsCnt1 = kWsCnt0 + 176ull * 8 * 4;       // [176][8] u32
constexpr size_t kWsRc   = kWsCnt1 + 176ull * 8 * 4;       // [2][8] u32
constexpr size_t kWsEnd  = kWsRc + 2ull * 8 * 4;
constexpr size_t kWsZeroBegin = kWsYacc;
constexpr size_t kWsZeroSize  = kWsEnd - kWsYacc;

DEV unsigned short f2bf(float f) {   // RNE float -> bf16
  unsigned u = __float_as_uint(f);
  u += 0x7fffu + ((u >> 16) & 1u);
  return (unsigned short)(u >> 16);
}
DEV float bf2f(unsigned short s) { return __uint_as_float(((unsigned)s) << 16); }
DEV float sigf(float v) { return 1.0f / (1.0f + __expf(-v)); }
DEV float tanhf_(float v) { float e = __expf(2.0f * v); return 1.0f - 2.0f / (e + 1.0f); }
DEV f32x16 zero16() {
  f32x16 z;
#pragma unroll
  for (int i = 0; i < 16; ++i) z[i] = 0.0f;
  return z;
}
DEV bf16x8 pack8(const float* p) {   // 8 consecutive fp32 -> bf16x8 fragment
  float4 a = *(const float4*)p;
  float4 b = *(const float4*)(p + 4);
  bf16x8 r;
  r[0] = (short)f2bf(a.x); r[1] = (short)f2bf(a.y);
  r[2] = (short)f2bf(a.z); r[3] = (short)f2bf(a.w);
  r[4] = (short)f2bf(b.x); r[5] = (short)f2bf(b.y);
  r[6] = (short)f2bf(b.z); r[7] = (short)f2bf(b.w);
  return r;
}
// bounded spin: true = condition met, false = timed out (~0.5s cap)
DEV bool waitcnt_ge(unsigned* p, unsigned tgt) {
  for (int it = 0; it < (1 << 22); ++it) {
    if (__hip_atomic_load(p, __ATOMIC_RELAXED, __HIP_MEMORY_SCOPE_AGENT) >= tgt)
      return true;
    __builtin_amdgcn_s_sleep(2);
  }
  return false;
}

// ---- chunked A staging: [64 rows x 128 k] bf16, XOR-swizzled 16B groups ----
#define STAGE_LOAD(c_)                                                        \
  { _Pragma("unroll") for (int it = 0; it < 4; ++it) {                        \
      const int lin = tid + it * 256;                                         \
      const int r_ = lin >> 4, g_ = lin & 15;                                 \
      ld[it] = *(const uint4*)&hrow[r_ * kHP + (c_)*128 + g_ * 8];            \
    } }

#define STAGE_STORE(c_)                                                       \
  { _Pragma("unroll") for (int it = 0; it < 4; ++it) {                        \
      const int lin = tid + it * 256;                                         \
      const int r_ = lin >> 4, g_ = lin & 15;                                 \
      *(uint4*)&chunkB[((c_)&1) * 8192 + r_ * 128 + ((g_ ^ (r_ & 15)) << 3)] = ld[it]; \
    } }

// wave kw handles ksteps {kw, kw+4} inside each 8-kstep chunk
#define MFMA_CHUNK(c_)                                                        \
  { _Pragma("unroll") for (int j2 = 0; j2 < 2; ++j2) {                        \
      const int jin = kw + j2 * 4;                                            \
      const int g0 = jin * 2 + hi5;                                           \
      const bf16x8 a0 = *(const bf16x8*)&chunkB[((c_)&1) * 8192 + l31 * 128 + ((g0 ^ l15) << 3)]; \
      const bf16x8 a1 = *(const bf16x8*)&chunkB[((c_)&1) * 8192 + (32 + l31) * 128 + ((g0 ^ l15) << 3)]; \
      acc00 = MFMA32(a0, wf[0][(c_)*2 + j2], acc00);                          \
      acc01 = MFMA32(a0, wf[1][(c_)*2 + j2], acc01);                          \
      acc10 = MFMA32(a1, wf[0][(c_)*2 + j2], acc10);                          \
      acc11 = MFMA32(a1, wf[1][(c_)*2 + j2], acc11);                          \
    } }

// C/D (32x32x16): col=lane&31, row=(reg&3)+4*(lane>>5)+8*(reg>>2)
#define PARTS_WRITE(accv, ms_, ns_)                                           \
  { const int gate_ = (ns_)*2 + gbit;                                         \
    _Pragma("unroll") for (int rg = 0; rg < 16; ++rg) {                       \
      const int r_ = (ms_)*32 + (rg & 3) + 4 * hi5 + 8 * (rg >> 2);           \
      partsB[((kw * 4 + gate_) * 64 + r_) * 16 + l15] = f2bf((accv)[rg]);     \
    } }

__global__ __launch_bounds__(256, 2) void lstm_persist(
    const float* __restrict__ x, const float* __restrict__ ft,
    const float* __restrict__ h0in, const float* __restrict__ c0in,
    const float* __restrict__ wih0, const float* __restrict__ whh0,
    const float* __restrict__ bih0, const float* __restrict__ bhh0,
    const float* __restrict__ wih1, const float* __restrict__ whh1,
    const float* __restrict__ bih1, const float* __restrict__ bhh1,
    const float* __restrict__ fcw, const float* __restrict__ fcb,
    float* __restrict__ out, char* __restrict__ ws) {
  // union region: A double-buffer (2x16KB) OR bf16 partial gates (32KB)
  __shared__ __attribute__((aligned(16))) char ubuf[32768];
  __shared__ __attribute__((aligned(16))) unsigned short xin[64 * 40];   // [64][32] pad 40
  __shared__ __attribute__((aligned(16))) unsigned short hloc[64 * 24];  // [64][16] pad 24
  __shared__ float biasl[4][16];
  __shared__ float fcwl[8][16];
  __shared__ unsigned bflag;

  unsigned short* chunkB = (unsigned short*)ubuf;
  unsigned short* partsB = (unsigned short*)ubuf;

  const int bid = blockIdx.x;
  const int layer = bid >> 8;          // bids 0-255: layer0, 256-511: layer1
  const int idx = bid & 255;
  const int bc = idx & 7;              // bc == bid%8 -> per-XCD locality
  const int hc = idx >> 3;             // 32 hidden slices of 16 units
  const int b0 = bc * kBT;
  const int u0 = hc * 16;
  const int tid = threadIdx.x;
  const int kw = tid >> 6;             // wave id = K-split slot
  const int lane = tid & 63;
  const int l31 = lane & 31;
  const int l15 = lane & 15;
  const int hi5 = lane >> 5;
  const int gbit = (lane >> 4) & 1;

  unsigned short* hbuf = (unsigned short*)(ws + kWsHbuf);
  float* yacc = (float*)(ws + kWsYacc);
  unsigned* cnt0 = (unsigned*)(ws + kWsCnt0);
  unsigned* cnt1 = (unsigned*)(ws + kWsCnt1);
  unsigned* rc = (unsigned*)(ws + kWsRc);

  bool alive = true;  // tid0-only: set false on spin timeout, skip all waits

  // ---- one-time: weights -> registers (bf16 B-fragments) ----
  // B-frag (32x32x16): n = lane&31, k = (lane>>5)*8 + j; our W is [gate-row][k].
  // col n -> gate = ns*2 + gbit, hidden = u0 + l15.
  bf16x8 wf[2][16];
#pragma unroll
  for (int ns = 0; ns < 2; ++ns) {
    const int gate = ns * 2 + gbit;
    const int wrow = gate * 512 + u0 + l15;
    if (layer) {
#pragma unroll
      for (int i = 0; i < 16; ++i) {
        const int jg = (i >> 1) * 8 + kw + (i & 1) * 4;  // global kstep
        const int k0 = jg * 16 + hi5 * 8;
        const float* p = (k0 < 512) ? (wih1 + wrow * 512 + k0)
                                    : (whh1 + wrow * 512 + (k0 - 512));
        wf[ns][i] = pack8(p);
      }
    } else {
#pragma unroll
      for (int i = 0; i < 8; ++i) {
        const int jg = (i >> 1) * 8 + kw + (i & 1) * 4;
        wf[ns][i] = pack8(whh0 + wrow * 512 + jg * 16 + hi5 * 8);
      }
      if (kw < 2) wf[ns][8] = pack8(wih0 + wrow * 32 + kw * 16 + hi5 * 8);
    }
  }

  if (tid < 64) {
    const int g = tid >> 4, h = tid & 15;
    const int row = g * 512 + u0 + h;
    biasl[g][h] = layer ? (bih1[row] + bhh1[row]) : (bih0[row] + bhh0[row]);
  }
  if (layer && tid >= 64 && tid < 192) {
    const int t2 = tid - 64;
    fcwl[t2 >> 4][t2 & 15] = fcw[(t2 >> 4) * 512 + u0 + (t2 & 15)];
  }

  // cell-state ownership: thread -> (rows own_r0..+3, hidden own_h); c fp32 in regs
  const int own_h = tid & 15;
  const int own_r0 = (tid >> 4) * 4;
  float cst[4];
  {
    const float cv = c0in[layer * 512 + u0 + own_h];
    cst[0] = cst[1] = cst[2] = cst[3] = cv;
  }

  // ---- prologue: write h(-1) slices, publish ----
  {
    const int pw0 = layer ? 0 : 1;   // L0 init read at t=0 (parity 1); L1 at t=0 (parity 0)
    if (tid < 128) {
      const int r = tid >> 1, half = tid & 1;
      union { unsigned short s[8]; uint4 q; } v;
#pragma unroll
      for (int k2 = 0; k2 < 8; ++k2)
        v.s[k2] = f2bf(h0in[layer * 512 + u0 + half * 8 + k2]);
      *(uint4*)&hbuf[(size_t)pw0 * 512 * kHP + (size_t)(b0 + r) * kHP +
                     layer * 512 + u0 + half * 8] = v.q;
    }
    __threadfence();
    __syncthreads();
    if (tid == 0)
      __hip_atomic_fetch_add((layer ? cnt1 : cnt0) + bc, 1u, __ATOMIC_RELAXED,
                             __HIP_MEMORY_SCOPE_AGENT);
  }

  auto xin_store = [&](int r, int c4, float4 v) {
    const int gx = c4 >> 3, half = (c4 >> 2) & 1;
    uint2 pv;
    pv.x = (unsigned)f2bf(v.x) | ((unsigned)f2bf(v.y) << 16);
    pv.y = (unsigned)f2bf(v.z) | ((unsigned)f2bf(v.w) << 16);
    *(uint2*)&xin[r * 40 + ((gx ^ (r & 3)) << 3) + half * 4] = pv;
  };

  auto cell_update = [&]() {
#pragma unroll
    for (int i = 0; i < 4; ++i) {
      const int r = own_r0 + i;
      float ig = biasl[0][own_h], fg = biasl[1][own_h];
      float gg = biasl[2][own_h], og = biasl[3][own_h];
#pragma unroll
      for (int w2 = 0; w2 < 4; ++w2) {
        ig += bf2f(partsB[((w2 * 4 + 0) * 64 + r) * 16 + own_h]);
        fg += bf2f(partsB[((w2 * 4 + 1) * 64 + r) * 16 + own_h]);
        gg += bf2f(partsB[((w2 * 4 + 2) * 64 + r) * 16 + own_h]);
        og += bf2f(partsB[((w2 * 4 + 3) * 64 + r) * 16 + own_h]);
      }
      const float cv = sigf(fg) * cst[i] + sigf(ig) * tanhf_(gg);
      cst[i] = cv;
      hloc[r * 24 + own_h] = f2bf(sigf(og) * tanhf_(cv));
    }
  };

  if (layer == 0) {
    // =========================== LAYER 0 blocks ===========================
    for (int t = 0; t < kT; ++t) {
      const int pr = (t - 1) & 1;     // read h0(t-1)
      const int pw = t & 1;           // write h0(t)
      if (t < kSeq) {
        // encoder input: x[t] (always ready)
#pragma unroll
        for (int it = 0; it < 2; ++it) {
          const int u = tid + it * 256;
          const int r = u >> 3, c4 = (u & 7) * 4;
          xin_store(r, c4, *(const float4*)&x[(size_t)(t * 512 + b0 + r) * 32 + c4]);
        }
      } else {
        // decoder input: y(t-1) (from yacc) ++ future_time[t-128]
        const int q = (t - 1) & 1;
        if (tid == 0 && alive) alive = waitcnt_ge(&cnt1[t * 8 + bc], kProd);
        __syncthreads();
        __threadfence();  // acquire
        if (tid < 128) {
          const int r = tid >> 1, o4 = (tid & 1) * 4;
          float4 v = *(const float4*)&yacc[(size_t)(q * 512 + b0 + r) * 8 + o4];
          const float4 bb = *(const float4*)&fcb[o4];
          v.x += bb.x; v.y += bb.y; v.z += bb.z; v.w += bb.w;
          if (hc == 0)
            *(float4*)&out[(size_t)((t - kSeq) * 512 + b0 + r) * 8 + o4] = v;
          xin_store(r, o4, v);
        }
        for (int u = tid; u < 384; u += 256) {
          const int r = u / 6, m = u - r * 6;
          xin_store(r, 8 + m * 4,
                    *(const float4*)&ft[(size_t)((t - kSeq) * 512 + b0 + r) * 24 + m * 4]);
        }
        __syncthreads();
        // last-reader zeros yacc[q] slice for reuse at t+2
        if (tid == 0) {
          const unsigned old = __hip_atomic_fetch_add(&rc[q * 8 + bc], 1u,
                                                      __ATOMIC_RELAXED, __HIP_MEMORY_SCOPE_AGENT);
          bflag = (old == kProd - 1) ? 1u : 0u;
        }
        __syncthreads();
        if (bflag) {
          for (int u = tid; u < 512; u += 256)
            yacc[(size_t)q * 512 * 8 + (size_t)b0 * 8 + u] = 0.0f;
          __threadfence();
          __syncthreads();
          if (tid == 0)
            __hip_atomic_store(&rc[q * 8 + bc], 0u, __ATOMIC_RELAXED, __HIP_MEMORY_SCOPE_AGENT);
        }
      }
      if (tid == 0 && alive) {
        alive = waitcnt_ge(&cnt0[t * 8 + bc], kProd);            // h0(t-1) ready
        if (alive && t >= 1 && t < kSeq)
          alive = waitcnt_ge(&cnt1[(t - 1) * 8 + bc], kProd);    // WAR guard
      }
      __syncthreads();
      __threadfence();  // acquire

      f32x16 acc00 = zero16(), acc01 = zero16(), acc10 = zero16(), acc11 = zero16();
      const unsigned short* hrow = hbuf + (size_t)pr * 512 * kHP + (size_t)b0 * kHP;
      uint4 ld[4];
      STAGE_LOAD(0);
      STAGE_STORE(0);
      __syncthreads();
#pragma unroll
      for (int c = 0; c < 4; ++c) {
        if (c < 3) STAGE_LOAD(c + 1);
        MFMA_CHUNK(c);
        __syncthreads();
        if (c < 3) { STAGE_STORE(c + 1); __syncthreads(); }
      }
      if (kw < 2) {  // x-part ksteps 32/33 handled by waves 0/1
#pragma unroll
        for (int ms = 0; ms < 2; ++ms) {
          const int r = ms * 32 + l31;
          const int gx = kw * 2 + hi5;
          const bf16x8 a = *(const bf16x8*)&xin[r * 40 + ((gx ^ (r & 3)) << 3)];
          if (ms == 0) {
            acc00 = MFMA32(a, wf[0][8], acc00);
            acc01 = MFMA32(a, wf[1][8], acc01);
          } else {
            acc10 = MFMA32(a, wf[0][8], acc10);
            acc11 = MFMA32(a, wf[1][8], acc11);
          }
        }
      }
      __syncthreads();
      PARTS_WRITE(acc00, 0, 0); PARTS_WRITE(acc01, 0, 1);
      PARTS_WRITE(acc10, 1, 0); PARTS_WRITE(acc11, 1, 1);
      __syncthreads();
      cell_update();
      __syncthreads();
      if (tid < 128) {
        const int r = tid >> 1, half = tid & 1;
        *(uint4*)&hbuf[(size_t)pw * 512 * kHP + (size_t)(b0 + r) * kHP + u0 + half * 8] =
            *(const uint4*)&hloc[r * 24 + half * 8];
      }
      __threadfence();  // release
      __syncthreads();
      if (tid == 0)
        __hip_atomic_fetch_add(&cnt0[(t + 1) * 8 + bc], 1u, __ATOMIC_RELAXED,
                               __HIP_MEMORY_SCOPE_AGENT);
    }
    // last prediction y(174) -> out[47]
    if (hc == 0) {
      if (tid == 0 && alive) alive = waitcnt_ge(&cnt1[kT * 8 + bc], kProd);
      __syncthreads();
      __threadfence();
      for (int u = tid; u < 512; u += 256) {
        const int r = u >> 3, o = u & 7;
        out[(size_t)(47 * 512 + b0 + r) * 8 + o] = yacc[(size_t)(b0 + r) * 8 + o] + fcb[o];
      }
    }
  } else {
    // =========================== LAYER 1 blocks ===========================
    for (int t = 0; t < kT; ++t) {
      const int pr = t & 1;          // read [h0(t) | h1(t-1)]
      const int pw = pr ^ 1;         // write h1(t)
      if (tid == 0 && alive) {
        alive = waitcnt_ge(&cnt0[(t + 1) * 8 + bc], kProd);      // h0(t)
        if (alive) alive = waitcnt_ge(&cnt1[t * 8 + bc], kProd); // h1(t-1)
      }
      __syncthreads();
      __threadfence();  // acquire

      f32x16 acc00 = zero16(), acc01 = zero16(), acc10 = zero16(), acc11 = zero16();
      const unsigned short* hrow = hbuf + (size_t)pr * 512 * kHP + (size_t)b0 * kHP;
      uint4 ld[4];
      STAGE_LOAD(0);
      STAGE_STORE(0);
      __syncthreads();
#pragma unroll
      for (int c = 0; c < 8; ++c) {
        if (c < 7) STAGE_LOAD(c + 1);
        MFMA_CHUNK(c);
        __syncthreads();
        if (c < 7) { STAGE_STORE(c + 1); __syncthreads(); }
      }
      PARTS_WRITE(acc00, 0, 0); PARTS_WRITE(acc01, 0, 1);
      PARTS_WRITE(acc10, 1, 0); PARTS_WRITE(acc11, 1, 1);
      __syncthreads();
      cell_update();
      __syncthreads();
      if (tid < 128) {
        const int r = tid >> 1, half = tid & 1;
        *(uint4*)&hbuf[(size_t)pw * 512 * kHP + (size_t)(b0 + r) * kHP + 512 + u0 + half * 8] =
            *(const uint4*)&hloc[r * 24 + half * 8];
      }
      if (t >= kSeq - 1) {  // y(t) partials: [64x16]@fc_w slice -> atomic fp32
        const int q = t & 1;
#pragma unroll
        for (int rep = 0; rep < 2; ++rep) {
          const int i2 = tid + rep * 256;
          const int r = i2 >> 3, o = i2 & 7;
          float s = 0.0f;
#pragma unroll
          for (int h2 = 0; h2 < 16; ++h2)
            s += bf2f(hloc[r * 24 + h2]) * fcwl[o][h2];
          atomicAdd(&yacc[(size_t)(q * 512 + b0 + r) * 8 + o], s);
        }
      }
      __threadfence();  // release
      __syncthreads();
      if (tid == 0)
        __hip_atomic_fetch_add(&cnt1[(t + 1) * 8 + bc], 1u, __ATOMIC_RELAXED,
                               __HIP_MEMORY_SCOPE_AGENT);
    }
  }
}

extern "C" void kernel_launch(void* const* d_in, const int* in_sizes, int n_in,
                              void* d_out, int out_size, void* d_ws, size_t ws_size,
                              hipStream_t stream) {
  (void)in_sizes; (void)n_in; (void)out_size; (void)ws_size;
  hipMemsetAsync((char*)d_ws + kWsZeroBegin, 0, kWsZeroSize, stream);

  const float* x    = (const float*)d_in[0];
  const float* ft   = (const float*)d_in[1];
  const float* h0in = (const float*)d_in[2];
  const float* c0in = (const float*)d_in[3];
  const float* wih0 = (const float*)d_in[4];
  const float* whh0 = (const float*)d_in[5];
  const float* bih0 = (const float*)d_in[6];
  const float* bhh0 = (const float*)d_in[7];
  const float* wih1 = (const float*)d_in[8];
  const float* whh1 = (const float*)d_in[9];
  const float* bih1 = (const float*)d_in[10];
  const float* bhh1 = (const float*)d_in[11];
  const float* fcw  = (const float*)d_in[12];
  const float* fcb  = (const float*)d_in[13];
  float* out = (float*)d_out;
  char* ws = (char*)d_ws;

  void* args[] = {&x, &ft, &h0in, &c0in, &wih0, &whh0, &bih0, &bhh0,
                  &wih1, &whh1, &bih1, &bhh1, &fcw, &fcb, &out, &ws};
  hipError_t err = hipLaunchCooperativeKernel((void*)lstm_persist, dim3(512),
                                              dim3(256), args, 0, stream);
  if (err != hipSuccess) {
    // fallback: plain launch; 2 blocks/CU occupancy is guaranteed by
    // __launch_bounds__(256,2) + 42KB LDS, so all 512 blocks co-reside.
    lstm_persist<<<dim3(512), dim3(256), 0, stream>>>(
        x, ft, h0in, c0in, wih0, whh0, bih0, bhh0,
        wih1, whh1, bih1, bhh1, fcw, fcb, out, ws);
  }
}

// Round 3
// 5484.359 us; speedup vs baseline: 3.2398x; 3.2398x over previous
//
#include <hip/hip_runtime.h>

// ---------------------------------------------------------------------------
// Persistent cooperative 2-layer LSTM encoder/decoder for MI355X (gfx950).
//   - 512 blocks x 256 thr (2 blocks/CU), co-resident.
//   - Weights live in VGPRs as bf16 MFMA B-fragments (loaded once).
//   - 4 waves/block split K (strided ksteps) -> staged A chunks read ONCE.
//   - bf16 partial-gate exchange in LDS, fp32 cell update, fp32 c in regs.
//   - FENCE-FREE cross-block protocol: all shared data moves via relaxed
//     agent-scope atomic dword loads/stores (device-coherent at L3); flag
//     posts use s_waitcnt(0) + relaxed atomic add. No __threadfence() ->
//     no buffer_wbl2/buffer_inv L2-flush storms (the round-2 17.8ms cause).
// ---------------------------------------------------------------------------

typedef __attribute__((ext_vector_type(8))) short bf16x8;
typedef __attribute__((ext_vector_type(16))) float f32x16;

#define MFMA32(a, b, c) __builtin_amdgcn_mfma_f32_32x32x16_bf16((a), (b), (c), 0, 0, 0)
#define DEV static __device__ __forceinline__

constexpr int kSeq = 128;          // encoder steps
constexpr int kT = 175;            // total lstm steps (128 + 47)
constexpr int kBT = 64;            // batch rows per block
constexpr int kProd = 32;          // producer blocks per (layer, bc)
constexpr int kHP = 1024;          // hbuf row pitch: cols 0-511 h0, 512-1023 h1

// workspace layout (bytes)
constexpr size_t kWsHbuf = 0;                              // [2][512][1024] bf16
constexpr size_t kWsYacc = 2ull * 512 * kHP * 2;           // [2][512][8] f32
constexpr size_t kWsCnt0 = kWsYacc + 2ull * 512 * 8 * 4;   // [176][8] u32
constexpr size_t kWsCnt1 = kWsCnt0 + 176ull * 8 * 4;       // [176][8] u32
constexpr size_t kWsRc   = kWsCnt1 + 176ull * 8 * 4;       // [2][8] u32
constexpr size_t kWsEnd  = kWsRc + 2ull * 8 * 4;
constexpr size_t kWsZeroBegin = kWsYacc;
constexpr size_t kWsZeroSize  = kWsEnd - kWsYacc;

DEV unsigned short f2bf(float f) {   // RNE float -> bf16
  unsigned u = __float_as_uint(f);
  u += 0x7fffu + ((u >> 16) & 1u);
  return (unsigned short)(u >> 16);
}
DEV float bf2f(unsigned short s) { return __uint_as_float(((unsigned)s) << 16); }
DEV float sigf(float v) { return 1.0f / (1.0f + __expf(-v)); }
DEV float tanhf_(float v) { float e = __expf(2.0f * v); return 1.0f - 2.0f / (e + 1.0f); }
DEV f32x16 zero16() {
  f32x16 z;
#pragma unroll
  for (int i = 0; i < 16; ++i) z[i] = 0.0f;
  return z;
}
DEV bf16x8 pack8(const float* p) {   // 8 consecutive fp32 -> bf16x8 fragment
  float4 a = *(const float4*)p;
  float4 b = *(const float4*)(p + 4);
  bf16x8 r;
  r[0] = (short)f2bf(a.x); r[1] = (short)f2bf(a.y);
  r[2] = (short)f2bf(a.z); r[3] = (short)f2bf(a.w);
  r[4] = (short)f2bf(b.x); r[5] = (short)f2bf(b.y);
  r[6] = (short)f2bf(b.z); r[7] = (short)f2bf(b.w);
  return r;
}

// device-coherent (agent-scope, L2-bypassing) primitives -------------------
DEV unsigned ald(const unsigned* p) {
  return __hip_atomic_load(p, __ATOMIC_RELAXED, __HIP_MEMORY_SCOPE_AGENT);
}
DEV void ast(unsigned* p, unsigned v) {
  __hip_atomic_store(p, v, __ATOMIC_RELAXED, __HIP_MEMORY_SCOPE_AGENT);
}
DEV float aldf(const float* p) {
  return __hip_atomic_load(p, __ATOMIC_RELAXED, __HIP_MEMORY_SCOPE_AGENT);
}
DEV void astf(float* p, float v) {
  __hip_atomic_store(p, v, __ATOMIC_RELAXED, __HIP_MEMORY_SCOPE_AGENT);
}
// release: drain outstanding (coherent) stores to the L3 coherence point,
// without any L2 writeback instruction.
DEV void relwait() {
  __atomic_signal_fence(__ATOMIC_SEQ_CST);
  __builtin_amdgcn_s_waitcnt(0);
  __atomic_signal_fence(__ATOMIC_SEQ_CST);
}
// bounded spin: true = condition met, false = timed out (~0.5s cap)
DEV bool waitcnt_ge(unsigned* p, unsigned tgt) {
  for (int it = 0; it < (1 << 22); ++it) {
    if (ald(p) >= tgt) { __atomic_signal_fence(__ATOMIC_ACQUIRE); return true; }
    __builtin_amdgcn_s_sleep(2);
  }
  return false;
}

// ---- chunked A staging: [64 rows x 128 k] bf16, XOR-swizzled 16B groups ----
// loads are agent-coherent dwords (hbuf written by other blocks/XCDs)
#define STAGE_LOAD(c_)                                                        \
  { _Pragma("unroll") for (int it = 0; it < 4; ++it) {                        \
      const int lin = tid + it * 256;                                         \
      const int r_ = lin >> 4, g_ = lin & 15;                                 \
      const unsigned* p_ = (const unsigned*)&hrow[r_ * kHP + (c_)*128 + g_ * 8]; \
      ld[it].x = ald(p_ + 0); ld[it].y = ald(p_ + 1);                         \
      ld[it].z = ald(p_ + 2); ld[it].w = ald(p_ + 3);                         \
    } }

#define STAGE_STORE(c_)                                                       \
  { _Pragma("unroll") for (int it = 0; it < 4; ++it) {                        \
      const int lin = tid + it * 256;                                         \
      const int r_ = lin >> 4, g_ = lin & 15;                                 \
      *(uint4*)&chunkB[((c_)&1) * 8192 + r_ * 128 + ((g_ ^ (r_ & 15)) << 3)] = ld[it]; \
    } }

// wave kw handles ksteps {kw, kw+4} inside each 8-kstep chunk
#define MFMA_CHUNK(c_)                                                        \
  { _Pragma("unroll") for (int j2 = 0; j2 < 2; ++j2) {                        \
      const int jin = kw + j2 * 4;                                            \
      const int g0 = jin * 2 + hi5;                                           \
      const bf16x8 a0 = *(const bf16x8*)&chunkB[((c_)&1) * 8192 + l31 * 128 + ((g0 ^ l15) << 3)]; \
      const bf16x8 a1 = *(const bf16x8*)&chunkB[((c_)&1) * 8192 + (32 + l31) * 128 + ((g0 ^ l15) << 3)]; \
      acc00 = MFMA32(a0, wf[0][(c_)*2 + j2], acc00);                          \
      acc01 = MFMA32(a0, wf[1][(c_)*2 + j2], acc01);                          \
      acc10 = MFMA32(a1, wf[0][(c_)*2 + j2], acc10);                          \
      acc11 = MFMA32(a1, wf[1][(c_)*2 + j2], acc11);                          \
    } }

// C/D (32x32x16): col=lane&31, row=(reg&3)+4*(lane>>5)+8*(reg>>2)
#define PARTS_WRITE(accv, ms_, ns_)                                           \
  { const int gate_ = (ns_)*2 + gbit;                                         \
    _Pragma("unroll") for (int rg = 0; rg < 16; ++rg) {                       \
      const int r_ = (ms_)*32 + (rg & 3) + 4 * hi5 + 8 * (rg >> 2);           \
      partsB[((kw * 4 + gate_) * 64 + r_) * 16 + l15] = f2bf((accv)[rg]);     \
    } }

__global__ __launch_bounds__(256, 2) void lstm_persist(
    const float* __restrict__ x, const float* __restrict__ ft,
    const float* __restrict__ h0in, const float* __restrict__ c0in,
    const float* __restrict__ wih0, const float* __restrict__ whh0,
    const float* __restrict__ bih0, const float* __restrict__ bhh0,
    const float* __restrict__ wih1, const float* __restrict__ whh1,
    const float* __restrict__ bih1, const float* __restrict__ bhh1,
    const float* __restrict__ fcw, const float* __restrict__ fcb,
    float* __restrict__ out, char* __restrict__ ws) {
  // union region: A double-buffer (2x16KB) OR bf16 partial gates (32KB)
  __shared__ __attribute__((aligned(16))) char ubuf[32768];
  __shared__ __attribute__((aligned(16))) unsigned short xin[64 * 40];   // [64][32] pad 40
  __shared__ __attribute__((aligned(16))) unsigned short hloc[64 * 24];  // [64][16] pad 24
  __shared__ float biasl[4][16];
  __shared__ float fcwl[8][16];
  __shared__ unsigned bflag;

  unsigned short* chunkB = (unsigned short*)ubuf;
  unsigned short* partsB = (unsigned short*)ubuf;

  const int bid = blockIdx.x;
  const int layer = bid >> 8;          // bids 0-255: layer0, 256-511: layer1
  const int idx = bid & 255;
  const int bc = idx & 7;              // bc == bid%8 -> per-XCD locality
  const int hc = idx >> 3;             // 32 hidden slices of 16 units
  const int b0 = bc * kBT;
  const int u0 = hc * 16;
  const int tid = threadIdx.x;
  const int kw = tid >> 6;             // wave id = K-split slot
  const int lane = tid & 63;
  const int l31 = lane & 31;
  const int l15 = lane & 15;
  const int hi5 = lane >> 5;
  const int gbit = (lane >> 4) & 1;

  unsigned short* hbuf = (unsigned short*)(ws + kWsHbuf);
  float* yacc = (float*)(ws + kWsYacc);
  unsigned* cnt0 = (unsigned*)(ws + kWsCnt0);
  unsigned* cnt1 = (unsigned*)(ws + kWsCnt1);
  unsigned* rc = (unsigned*)(ws + kWsRc);

  bool alive = true;  // tid0-only: set false on spin timeout, skip all waits

  // ---- one-time: weights -> registers (bf16 B-fragments) ----
  // B-frag (32x32x16): n = lane&31, k = (lane>>5)*8 + j; our W is [gate-row][k].
  // col n -> gate = ns*2 + gbit, hidden = u0 + l15.
  bf16x8 wf[2][16];
#pragma unroll
  for (int ns = 0; ns < 2; ++ns) {
    const int gate = ns * 2 + gbit;
    const int wrow = gate * 512 + u0 + l15;
    if (layer) {
#pragma unroll
      for (int i = 0; i < 16; ++i) {
        const int jg = (i >> 1) * 8 + kw + (i & 1) * 4;  // global kstep
        const int k0 = jg * 16 + hi5 * 8;
        const float* p = (k0 < 512) ? (wih1 + wrow * 512 + k0)
                                    : (whh1 + wrow * 512 + (k0 - 512));
        wf[ns][i] = pack8(p);
      }
    } else {
#pragma unroll
      for (int i = 0; i < 8; ++i) {
        const int jg = (i >> 1) * 8 + kw + (i & 1) * 4;
        wf[ns][i] = pack8(whh0 + wrow * 512 + jg * 16 + hi5 * 8);
      }
      if (kw < 2) wf[ns][8] = pack8(wih0 + wrow * 32 + kw * 16 + hi5 * 8);
    }
  }

  if (tid < 64) {
    const int g = tid >> 4, h = tid & 15;
    const int row = g * 512 + u0 + h;
    biasl[g][h] = layer ? (bih1[row] + bhh1[row]) : (bih0[row] + bhh0[row]);
  }
  if (layer && tid >= 64 && tid < 192) {
    const int t2 = tid - 64;
    fcwl[t2 >> 4][t2 & 15] = fcw[(t2 >> 4) * 512 + u0 + (t2 & 15)];
  }

  // cell-state ownership: thread -> (rows own_r0..+3, hidden own_h); c fp32 in regs
  const int own_h = tid & 15;
  const int own_r0 = (tid >> 4) * 4;
  float cst[4];
  {
    const float cv = c0in[layer * 512 + u0 + own_h];
    cst[0] = cst[1] = cst[2] = cst[3] = cv;
  }

  // ---- prologue: write h(-1) slices (coherent stores), publish ----
  {
    const int pw0 = layer ? 0 : 1;   // L0 init read at t=0 (parity 1); L1 at t=0 (parity 0)
    if (tid < 128) {
      const int r = tid >> 1, half = tid & 1;
      union { unsigned short s[8]; unsigned d[4]; } v;
#pragma unroll
      for (int k2 = 0; k2 < 8; ++k2)
        v.s[k2] = f2bf(h0in[layer * 512 + u0 + half * 8 + k2]);
      unsigned* dst = (unsigned*)&hbuf[(size_t)pw0 * 512 * kHP + (size_t)(b0 + r) * kHP +
                                       layer * 512 + u0 + half * 8];
#pragma unroll
      for (int k2 = 0; k2 < 4; ++k2) ast(dst + k2, v.d[k2]);
    }
    relwait();
    __syncthreads();
    if (tid == 0)
      __hip_atomic_fetch_add((layer ? cnt1 : cnt0) + bc, 1u, __ATOMIC_RELAXED,
                             __HIP_MEMORY_SCOPE_AGENT);
  }

  auto xin_store = [&](int r, int c4, float4 v) {
    const int gx = c4 >> 3, half = (c4 >> 2) & 1;
    uint2 pv;
    pv.x = (unsigned)f2bf(v.x) | ((unsigned)f2bf(v.y) << 16);
    pv.y = (unsigned)f2bf(v.z) | ((unsigned)f2bf(v.w) << 16);
    *(uint2*)&xin[r * 40 + ((gx ^ (r & 3)) << 3) + half * 4] = pv;
  };

  auto cell_update = [&]() {
#pragma unroll
    for (int i = 0; i < 4; ++i) {
      const int r = own_r0 + i;
      float ig = biasl[0][own_h], fg = biasl[1][own_h];
      float gg = biasl[2][own_h], og = biasl[3][own_h];
#pragma unroll
      for (int w2 = 0; w2 < 4; ++w2) {
        ig += bf2f(partsB[((w2 * 4 + 0) * 64 + r) * 16 + own_h]);
        fg += bf2f(partsB[((w2 * 4 + 1) * 64 + r) * 16 + own_h]);
        gg += bf2f(partsB[((w2 * 4 + 2) * 64 + r) * 16 + own_h]);
        og += bf2f(partsB[((w2 * 4 + 3) * 64 + r) * 16 + own_h]);
      }
      const float cv = sigf(fg) * cst[i] + sigf(ig) * tanhf_(gg);
      cst[i] = cv;
      hloc[r * 24 + own_h] = f2bf(sigf(og) * tanhf_(cv));
    }
  };

  // coherent h-slice publish: 64 rows x 16 cols bf16 from hloc
  auto h_publish = [&](int pw, int colbase) {
    if (tid < 128) {
      const int r = tid >> 1, half = tid & 1;
      union { uint4 q; unsigned d[4]; } v;
      v.q = *(const uint4*)&hloc[r * 24 + half * 8];
      unsigned* dst = (unsigned*)&hbuf[(size_t)pw * 512 * kHP +
                                       (size_t)(b0 + r) * kHP + colbase + half * 8];
#pragma unroll
      for (int k2 = 0; k2 < 4; ++k2) ast(dst + k2, v.d[k2]);
    }
  };

  if (layer == 0) {
    // =========================== LAYER 0 blocks ===========================
    for (int t = 0; t < kT; ++t) {
      const int pr = (t - 1) & 1;     // read h0(t-1)
      const int pw = t & 1;           // write h0(t)
      if (t < kSeq) {
        // encoder input: x[t] (always ready, plain loads)
#pragma unroll
        for (int it = 0; it < 2; ++it) {
          const int u = tid + it * 256;
          const int r = u >> 3, c4 = (u & 7) * 4;
          xin_store(r, c4, *(const float4*)&x[(size_t)(t * 512 + b0 + r) * 32 + c4]);
        }
      } else {
        // decoder input: y(t-1) (from yacc, coherent) ++ future_time[t-128]
        const int q = (t - 1) & 1;
        if (tid == 0 && alive) alive = waitcnt_ge(&cnt1[t * 8 + bc], kProd);
        __syncthreads();
        if (tid < 128) {
          const int r = tid >> 1, o4 = (tid & 1) * 4;
          const float* yp = &yacc[(size_t)(q * 512 + b0 + r) * 8 + o4];
          float4 v;
          v.x = aldf(yp + 0); v.y = aldf(yp + 1);
          v.z = aldf(yp + 2); v.w = aldf(yp + 3);
          const float4 bb = *(const float4*)&fcb[o4];
          v.x += bb.x; v.y += bb.y; v.z += bb.z; v.w += bb.w;
          if (hc == 0)
            *(float4*)&out[(size_t)((t - kSeq) * 512 + b0 + r) * 8 + o4] = v;
          xin_store(r, o4, v);
        }
        for (int u = tid; u < 384; u += 256) {
          const int r = u / 6, m = u - r * 6;
          xin_store(r, 8 + m * 4,
                    *(const float4*)&ft[(size_t)((t - kSeq) * 512 + b0 + r) * 24 + m * 4]);
        }
        __syncthreads();
        // last-reader zeros yacc[q] slice for reuse at t+2
        if (tid == 0) {
          const unsigned old = __hip_atomic_fetch_add(&rc[q * 8 + bc], 1u,
                                                      __ATOMIC_RELAXED, __HIP_MEMORY_SCOPE_AGENT);
          bflag = (old == kProd - 1) ? 1u : 0u;
        }
        __syncthreads();
        if (bflag) {
          for (int u = tid; u < 512; u += 256)
            astf(&yacc[(size_t)q * 512 * 8 + (size_t)b0 * 8 + u], 0.0f);
          relwait();
          __syncthreads();
          if (tid == 0)
            __hip_atomic_store(&rc[q * 8 + bc], 0u, __ATOMIC_RELAXED, __HIP_MEMORY_SCOPE_AGENT);
        }
      }
      if (tid == 0 && alive) {
        alive = waitcnt_ge(&cnt0[t * 8 + bc], kProd);            // h0(t-1) ready
        if (alive && t >= 1 && t < kSeq)
          alive = waitcnt_ge(&cnt1[(t - 1) * 8 + bc], kProd);    // WAR guard
      }
      __syncthreads();

      f32x16 acc00 = zero16(), acc01 = zero16(), acc10 = zero16(), acc11 = zero16();
      const unsigned short* hrow = hbuf + (size_t)pr * 512 * kHP + (size_t)b0 * kHP;
      uint4 ld[4];
      STAGE_LOAD(0);
      STAGE_STORE(0);
      __syncthreads();
#pragma unroll
      for (int c = 0; c < 4; ++c) {
        if (c < 3) STAGE_LOAD(c + 1);
        MFMA_CHUNK(c);
        __syncthreads();
        if (c < 3) { STAGE_STORE(c + 1); __syncthreads(); }
      }
      if (kw < 2) {  // x-part ksteps 32/33 handled by waves 0/1
#pragma unroll
        for (int ms = 0; ms < 2; ++ms) {
          const int r = ms * 32 + l31;
          const int gx = kw * 2 + hi5;
          const bf16x8 a = *(const bf16x8*)&xin[r * 40 + ((gx ^ (r & 3)) << 3)];
          if (ms == 0) {
            acc00 = MFMA32(a, wf[0][8], acc00);
            acc01 = MFMA32(a, wf[1][8], acc01);
          } else {
            acc10 = MFMA32(a, wf[0][8], acc10);
            acc11 = MFMA32(a, wf[1][8], acc11);
          }
        }
      }
      __syncthreads();
      PARTS_WRITE(acc00, 0, 0); PARTS_WRITE(acc01, 0, 1);
      PARTS_WRITE(acc10, 1, 0); PARTS_WRITE(acc11, 1, 1);
      __syncthreads();
      cell_update();
      __syncthreads();
      h_publish(pw, u0);
      relwait();
      __syncthreads();
      if (tid == 0)
        __hip_atomic_fetch_add(&cnt0[(t + 1) * 8 + bc], 1u, __ATOMIC_RELAXED,
                               __HIP_MEMORY_SCOPE_AGENT);
    }
    // last prediction y(174) -> out[47]
    if (hc == 0) {
      if (tid == 0 && alive) alive = waitcnt_ge(&cnt1[kT * 8 + bc], kProd);
      __syncthreads();
      for (int u = tid; u < 512; u += 256) {
        const int r = u >> 3, o = u & 7;
        out[(size_t)(47 * 512 + b0 + r) * 8 + o] =
            aldf(&yacc[(size_t)(b0 + r) * 8 + o]) + fcb[o];
      }
    }
  } else {
    // =========================== LAYER 1 blocks ===========================
    for (int t = 0; t < kT; ++t) {
      const int pr = t & 1;          // read [h0(t) | h1(t-1)]
      const int pw = pr ^ 1;         // write h1(t)
      if (tid == 0 && alive) {
        alive = waitcnt_ge(&cnt0[(t + 1) * 8 + bc], kProd);      // h0(t)
        if (alive) alive = waitcnt_ge(&cnt1[t * 8 + bc], kProd); // h1(t-1)
      }
      __syncthreads();

      f32x16 acc00 = zero16(), acc01 = zero16(), acc10 = zero16(), acc11 = zero16();
      const unsigned short* hrow = hbuf + (size_t)pr * 512 * kHP + (size_t)b0 * kHP;
      uint4 ld[4];
      STAGE_LOAD(0);
      STAGE_STORE(0);
      __syncthreads();
#pragma unroll
      for (int c = 0; c < 8; ++c) {
        if (c < 7) STAGE_LOAD(c + 1);
        MFMA_CHUNK(c);
        __syncthreads();
        if (c < 7) { STAGE_STORE(c + 1); __syncthreads(); }
      }
      PARTS_WRITE(acc00, 0, 0); PARTS_WRITE(acc01, 0, 1);
      PARTS_WRITE(acc10, 1, 0); PARTS_WRITE(acc11, 1, 1);
      __syncthreads();
      cell_update();
      __syncthreads();
      h_publish(pw, 512 + u0);
      if (t >= kSeq - 1) {  // y(t) partials: [64x16]@fc_w slice -> atomic fp32
        const int q = t & 1;
#pragma unroll
        for (int rep = 0; rep < 2; ++rep) {
          const int i2 = tid + rep * 256;
          const int r = i2 >> 3, o = i2 & 7;
          float s = 0.0f;
#pragma unroll
          for (int h2 = 0; h2 < 16; ++h2)
            s += bf2f(hloc[r * 24 + h2]) * fcwl[o][h2];
          atomicAdd(&yacc[(size_t)(q * 512 + b0 + r) * 8 + o], s);
        }
      }
      relwait();
      __syncthreads();
      if (tid == 0)
        __hip_atomic_fetch_add(&cnt1[(t + 1) * 8 + bc], 1u, __ATOMIC_RELAXED,
                               __HIP_MEMORY_SCOPE_AGENT);
    }
  }
}

extern "C" void kernel_launch(void* const* d_in, const int* in_sizes, int n_in,
                              void* d_out, int out_size, void* d_ws, size_t ws_size,
                              hipStream_t stream) {
  (void)in_sizes; (void)n_in; (void)out_size; (void)ws_size;
  hipMemsetAsync((char*)d_ws + kWsZeroBegin, 0, kWsZeroSize, stream);

  const float* x    = (const float*)d_in[0];
  const float* ft   = (const float*)d_in[1];
  const float* h0in = (const float*)d_in[2];
  const float* c0in = (const float*)d_in[3];
  const float* wih0 = (const float*)d_in[4];
  const float* whh0 = (const float*)d_in[5];
  const float* bih0 = (const float*)d_in[6];
  const float* bhh0 = (const float*)d_in[7];
  const float* wih1 = (const float*)d_in[8];
  const float* whh1 = (const float*)d_in[9];
  const float* bih1 = (const float*)d_in[10];
  const float* bhh1 = (const float*)d_in[11];
  const float* fcw  = (const float*)d_in[12];
  const float* fcb  = (const float*)d_in[13];
  float* out = (float*)d_out;
  char* ws = (char*)d_ws;

  void* args[] = {&x, &ft, &h0in, &c0in, &wih0, &whh0, &bih0, &bhh0,
                  &wih1, &whh1, &bih1, &bhh1, &fcw, &fcb, &out, &ws};
  hipError_t err = hipLaunchCooperativeKernel((void*)lstm_persist, dim3(512),
                                              dim3(256), args, 0, stream);
  if (err != hipSuccess) {
    // fallback: plain launch; 2 blocks/CU occupancy is guaranteed by
    // __launch_bounds__(256,2) + 42KB LDS, so all 512 blocks co-reside.
    lstm_persist<<<dim3(512), dim3(256), 0, stream>>>(
        x, ft, h0in, c0in, wih0, whh0, bih0, bhh0,
        wih1, whh1, bih1, bhh1, fcw, fcb, out, ws);
  }
}

// Round 4
// 3361.262 us; speedup vs baseline: 5.2863x; 1.6316x over previous
//
#include <hip/hip_runtime.h>

// ---------------------------------------------------------------------------
// Persistent 2-layer LSTM for MI355X (gfx950). Round-4 structure:
//   - 512 blocks x 256 thr (2/CU). Weights in regs as bf16 B-fragments.
//   - h stored FRAGMENT-MAJOR in ws: addr(r,k) = (k>>3)*1024 + r*16 + (k&7)*2
//     per (parity,layer,bc) region -> MFMA A-fragments are contiguous 16B.
//   - K-loop: direct global->VGPR coherent u64 loads, 4-kstep groups,
//     1-group lookahead, ZERO LDS staging, ZERO barriers inside the loop.
//   - Sync: per-producer 64B-padded stamp slots (no fetch_add contention);
//     wave0 polls 64 slots in parallel via one ballot loop.
//   - partsB stride 17 shorts (+1 pad) to kill 8-way LDS bank conflicts.
//   - Fence-free coherence: relaxed agent-scope atomics + s_waitcnt release.
// ---------------------------------------------------------------------------

typedef __attribute__((ext_vector_type(8))) short bf16x8;
typedef __attribute__((ext_vector_type(16))) float f32x16;

#define MFMA32(a, b, c) __builtin_amdgcn_mfma_f32_32x32x16_bf16((a), (b), (c), 0, 0, 0)
#define DEV static __device__ __forceinline__

constexpr int kSeq = 128;          // encoder steps
constexpr int kT = 175;            // total lstm steps
constexpr int kRB = 65536;         // bytes per (parity,layer,bc) h region

// workspace layout (bytes)
constexpr size_t kWsHbuf = 0;                               // [2][2][8] regions = 2 MB
constexpr size_t kWsYacc = 2ull * 2 * 8 * kRB;              // [2][512][8] f32 = 32 KB
constexpr size_t kWsFlag = kWsYacc + 2ull * 512 * 8 * 4;    // [2][8][32] x 64B = 32 KB
constexpr size_t kWsRc   = kWsFlag + 2ull * 8 * 32 * 64;    // [2][8] x 64B
constexpr size_t kWsEnd  = kWsRc + 2ull * 8 * 64;
constexpr size_t kWsZeroBegin = kWsYacc;
constexpr size_t kWsZeroSize  = kWsEnd - kWsYacc;

DEV unsigned short f2bf(float f) {
  unsigned u = __float_as_uint(f);
  u += 0x7fffu + ((u >> 16) & 1u);
  return (unsigned short)(u >> 16);
}
DEV float bf2f(unsigned short s) { return __uint_as_float(((unsigned)s) << 16); }
DEV float sigf(float v) { return 1.0f / (1.0f + __expf(-v)); }
DEV float tanhf_(float v) { float e = __expf(2.0f * v); return 1.0f - 2.0f / (e + 1.0f); }
DEV f32x16 zero16() {
  f32x16 z;
#pragma unroll
  for (int i = 0; i < 16; ++i) z[i] = 0.0f;
  return z;
}
DEV bf16x8 pack8(const float* p) {
  float4 a = *(const float4*)p;
  float4 b = *(const float4*)(p + 4);
  bf16x8 r;
  r[0] = (short)f2bf(a.x); r[1] = (short)f2bf(a.y);
  r[2] = (short)f2bf(a.z); r[3] = (short)f2bf(a.w);
  r[4] = (short)f2bf(b.x); r[5] = (short)f2bf(b.y);
  r[6] = (short)f2bf(b.z); r[7] = (short)f2bf(b.w);
  return r;
}

// device-coherent (agent-scope) primitives ---------------------------------
DEV unsigned ald(const unsigned* p) {
  return __hip_atomic_load(p, __ATOMIC_RELAXED, __HIP_MEMORY_SCOPE_AGENT);
}
DEV void ast(unsigned* p, unsigned v) {
  __hip_atomic_store(p, v, __ATOMIC_RELAXED, __HIP_MEMORY_SCOPE_AGENT);
}
DEV unsigned long long ald64(const unsigned long long* p) {
  return __hip_atomic_load(p, __ATOMIC_RELAXED, __HIP_MEMORY_SCOPE_AGENT);
}
DEV void ast64(unsigned long long* p, unsigned long long v) {
  __hip_atomic_store(p, v, __ATOMIC_RELAXED, __HIP_MEMORY_SCOPE_AGENT);
}
DEV float aldf(const float* p) {
  return __hip_atomic_load(p, __ATOMIC_RELAXED, __HIP_MEMORY_SCOPE_AGENT);
}
DEV void astf(float* p, float v) {
  __hip_atomic_store(p, v, __ATOMIC_RELAXED, __HIP_MEMORY_SCOPE_AGENT);
}
DEV void relwait() {  // drain own coherent stores to the coherence point
  __atomic_signal_fence(__ATOMIC_SEQ_CST);
  __builtin_amdgcn_s_waitcnt(0);
  __atomic_signal_fence(__ATOMIC_SEQ_CST);
}
// wave-parallel bounded poll: every lane has its own slot/threshold.
DEV bool pollw(const unsigned* slot, unsigned thr) {
  for (int it = 0; it < (1 << 22); ++it) {
    const unsigned v = ald(slot);
    if (__ballot(v < thr) == 0ull) {
      __atomic_signal_fence(__ATOMIC_ACQUIRE);
      return true;
    }
    __builtin_amdgcn_s_sleep(1);
  }
  return false;
}

// parts: [16 (kw,gate)][64 r][17 pad] bf16
#define PARTS_WRITE(accv, ms_, ns_)                                           \
  { const int gate_ = (ns_)*2 + gbit;                                         \
    _Pragma("unroll") for (int rg = 0; rg < 16; ++rg) {                       \
      const int r_ = (ms_)*32 + (rg & 3) + 4 * hi5 + 8 * (rg >> 2);           \
      partsB[((kw * 4 + gate_) * 64 + r_) * 17 + l15] = f2bf((accv)[rg]);     \
    } }

__global__ __launch_bounds__(256, 2) void lstm_persist(
    const float* __restrict__ x, const float* __restrict__ ft,
    const float* __restrict__ h0in, const float* __restrict__ c0in,
    const float* __restrict__ wih0, const float* __restrict__ whh0,
    const float* __restrict__ bih0, const float* __restrict__ bhh0,
    const float* __restrict__ wih1, const float* __restrict__ whh1,
    const float* __restrict__ bih1, const float* __restrict__ bhh1,
    const float* __restrict__ fcw, const float* __restrict__ fcb,
    float* __restrict__ out, char* __restrict__ ws) {
  __shared__ __attribute__((aligned(16))) unsigned short partsB[16 * 64 * 17];
  __shared__ __attribute__((aligned(16))) unsigned short xin[64 * 40];
  __shared__ __attribute__((aligned(16))) unsigned short hloc[64 * 24];
  __shared__ float biasl[4][16];
  __shared__ float fcwl[8][16];
  __shared__ unsigned bflag;

  const int bid = blockIdx.x;
  const int layer = bid >> 8;
  const int idx = bid & 255;
  const int bc = idx & 7;
  const int hc = idx >> 3;
  const int b0 = bc * 64;
  const int u0 = hc * 16;
  const int tid = threadIdx.x;
  const int kw = tid >> 6;
  const int lane = tid & 63;
  const int l31 = lane & 31, l15 = lane & 15, hi5 = lane >> 5, gbit = (lane >> 4) & 1;

  char* hbuf = ws + kWsHbuf;
  float* yacc = (float*)(ws + kWsYacc);
  unsigned* flg = (unsigned*)(ws + kWsFlag);
  unsigned* rc = (unsigned*)(ws + kWsRc);

  auto fslot = [&](int l, int b, int h) { return flg + (((l * 8) + b) * 32 + h) * 16; };
  auto region = [&](int p, int l, int b) -> char* {
    return hbuf + (size_t)(((p * 2) + l) * 8 + b) * kRB;
  };

  bool alive = true;  // wave0 lanes: poll timeout kill-switch

  // ---- one-time: weights -> registers (bf16 B-fragments), index by m ----
  // wave kw handles ksteps jin = kw + 4m.  B-frag: n=lane&31, k=hi5*8+j.
  bf16x8 wf[2][16];
#pragma unroll
  for (int ns = 0; ns < 2; ++ns) {
    const int gate = ns * 2 + gbit;
    const int wrow = gate * 512 + u0 + l15;
    if (layer) {
#pragma unroll
      for (int m = 0; m < 16; ++m) {
        const int jg = kw + 4 * m;
        const int k0 = jg * 16 + hi5 * 8;
        const float* p = (k0 < 512) ? (wih1 + wrow * 512 + k0)
                                    : (whh1 + wrow * 512 + (k0 - 512));
        wf[ns][m] = pack8(p);
      }
    } else {
#pragma unroll
      for (int m = 0; m < 8; ++m) {
        const int jg = kw + 4 * m;
        wf[ns][m] = pack8(whh0 + wrow * 512 + jg * 16 + hi5 * 8);
      }
      if (kw < 2) wf[ns][8] = pack8(wih0 + wrow * 32 + kw * 16 + hi5 * 8);
    }
  }

  if (tid < 64) {
    const int g = tid >> 4, h = tid & 15;
    const int row = g * 512 + u0 + h;
    biasl[g][h] = layer ? (bih1[row] + bhh1[row]) : (bih0[row] + bhh0[row]);
  }
  if (layer && tid >= 64 && tid < 192) {
    const int t2 = tid - 64;
    fcwl[t2 >> 4][t2 & 15] = fcw[(t2 >> 4) * 512 + u0 + (t2 & 15)];
  }

  const int own_h = tid & 15;
  const int own_r0 = (tid >> 4) * 4;
  float cst[4];
  {
    const float cv = c0in[layer * 512 + u0 + own_h];
    cst[0] = cst[1] = cst[2] = cst[3] = cv;
  }

  // ---- prologue: write h(-1) into fragment-major region, stamp 1 ----
  {
    char* dst = region(layer ? 0 : 1, layer, bc);
    if (tid < 128) {
      const int r = tid >> 1, half = tid & 1;
      union { unsigned short s[8]; unsigned long long u[2]; } v;
#pragma unroll
      for (int k2 = 0; k2 < 8; ++k2)
        v.s[k2] = f2bf(h0in[layer * 512 + u0 + half * 8 + k2]);
      unsigned long long* dp =
          (unsigned long long*)(dst + ((u0 >> 3) + half) * 1024 + r * 16);
      ast64(dp, v.u[0]); ast64(dp + 1, v.u[1]);
    }
    relwait();
    __syncthreads();
    if (tid == 0) ast(fslot(layer, bc, hc), 1u);
  }

  auto xin_store = [&](int r, int c4, float4 v) {
    const int gx = c4 >> 3, half = (c4 >> 2) & 1;
    uint2 pv;
    pv.x = (unsigned)f2bf(v.x) | ((unsigned)f2bf(v.y) << 16);
    pv.y = (unsigned)f2bf(v.z) | ((unsigned)f2bf(v.w) << 16);
    *(uint2*)&xin[r * 40 + ((gx ^ (r & 3)) << 3) + half * 4] = pv;
  };

  auto cell_update = [&]() {
#pragma unroll
    for (int i = 0; i < 4; ++i) {
      const int r = own_r0 + i;
      float ig = biasl[0][own_h], fg = biasl[1][own_h];
      float gg = biasl[2][own_h], og = biasl[3][own_h];
#pragma unroll
      for (int w2 = 0; w2 < 4; ++w2) {
        ig += bf2f(partsB[((w2 * 4 + 0) * 64 + r) * 17 + own_h]);
        fg += bf2f(partsB[((w2 * 4 + 1) * 64 + r) * 17 + own_h]);
        gg += bf2f(partsB[((w2 * 4 + 2) * 64 + r) * 17 + own_h]);
        og += bf2f(partsB[((w2 * 4 + 3) * 64 + r) * 17 + own_h]);
      }
      const float cv = sigf(fg) * cst[i] + sigf(ig) * tanhf_(gg);
      cst[i] = cv;
      hloc[r * 24 + own_h] = f2bf(sigf(og) * tanhf_(cv));
    }
  };

  auto h_publish = [&](char* dst) {  // 64 r x 16 units, coherent u64 stores
    if (tid < 128) {
      const int r = tid >> 1, half = tid & 1;
      union { uint4 q; unsigned long long u[2]; } v;
      v.q = *(const uint4*)&hloc[r * 24 + half * 8];
      unsigned long long* dp =
          (unsigned long long*)(dst + ((u0 >> 3) + half) * 1024 + r * 16);
      ast64(dp, v.u[0]); ast64(dp + 1, v.u[1]);
    }
  };

  if (layer == 0) {
    // =========================== LAYER 0 ===========================
    for (int t = 0; t < kT; ++t) {
      // combined wait: h0(t-1) ready (stamp>=t+1); flag1: WAR (>=t) or y (>=t+1)
      if (kw == 0 && alive) {
        const unsigned* slot = (lane < 32)
            ? fslot(0, bc, lane)
            : fslot(1, bc, lane - 32);
        const unsigned thr = (lane < 32)
            ? (unsigned)(t + 1)
            : (unsigned)((t < kSeq) ? t : t + 1);
        alive = pollw(slot, thr);
      }
      __syncthreads();

      if (t < kSeq) {
#pragma unroll
        for (int it = 0; it < 2; ++it) {
          const int u = tid + it * 256;
          const int r = u >> 3, c4 = (u & 7) * 4;
          xin_store(r, c4, *(const float4*)&x[(size_t)(t * 512 + b0 + r) * 32 + c4]);
        }
        __syncthreads();  // xin ready
      } else {
        const int q = (t - 1) & 1;
        if (tid < 128) {
          const int r = tid >> 1, o4 = (tid & 1) * 4;
          const float* yp = &yacc[(size_t)(q * 512 + b0 + r) * 8 + o4];
          float4 v;
          v.x = aldf(yp + 0); v.y = aldf(yp + 1);
          v.z = aldf(yp + 2); v.w = aldf(yp + 3);
          const float4 bb = *(const float4*)&fcb[o4];
          v.x += bb.x; v.y += bb.y; v.z += bb.z; v.w += bb.w;
          if (hc == 0)
            *(float4*)&out[(size_t)((t - kSeq) * 512 + b0 + r) * 8 + o4] = v;
          xin_store(r, o4, v);
        }
        for (int u = tid; u < 384; u += 256) {
          const int r = u / 6, m = u - r * 6;
          xin_store(r, 8 + m * 4,
                    *(const float4*)&ft[(size_t)((t - kSeq) * 512 + b0 + r) * 24 + m * 4]);
        }
        __syncthreads();  // xin ready, yacc reads done
        if (tid == 0) {
          const unsigned old = __hip_atomic_fetch_add(rc + (q * 8 + bc) * 16, 1u,
                                                      __ATOMIC_RELAXED,
                                                      __HIP_MEMORY_SCOPE_AGENT);
          bflag = (old == 31u) ? 1u : 0u;
        }
        __syncthreads();
        if (bflag) {  // last reader zeroes yacc[q] slice for reuse
          for (int u = tid; u < 512; u += 256)
            astf(&yacc[(size_t)q * 512 * 8 + (size_t)b0 * 8 + u], 0.0f);
          relwait();
          __syncthreads();
          if (tid == 0) ast(rc + (q * 8 + bc) * 16, 0u);
        }
      }

      // K-loop: 8 ksteps (jin = kw+4m, m=0..7), direct coherent A loads
      f32x16 acc00 = zero16(), acc01 = zero16(), acc10 = zero16(), acc11 = zero16();
      const char* hb0 = region((t - 1) & 1, 0, bc);
      unsigned long long abuf[2][16];
#pragma unroll
      for (int i = 0; i < 4; ++i) {  // prefetch group 0
        const size_t off = (size_t)((2 * (kw + 4 * i) + hi5) * 64 + l31) * 16;
        const unsigned long long* p = (const unsigned long long*)(hb0 + off);
        abuf[0][i * 4 + 0] = ald64(p);
        abuf[0][i * 4 + 1] = ald64(p + 1);
        const unsigned long long* q2 = (const unsigned long long*)(hb0 + off + 512);
        abuf[0][i * 4 + 2] = ald64(q2);
        abuf[0][i * 4 + 3] = ald64(q2 + 1);
      }
#pragma unroll
      for (int g = 0; g < 2; ++g) {
        if (g == 0) {
#pragma unroll
          for (int i = 0; i < 4; ++i) {
            const int m = 4 + i;
            const size_t off = (size_t)((2 * (kw + 4 * m) + hi5) * 64 + l31) * 16;
            const unsigned long long* p = (const unsigned long long*)(hb0 + off);
            abuf[1][i * 4 + 0] = ald64(p);
            abuf[1][i * 4 + 1] = ald64(p + 1);
            const unsigned long long* q2 = (const unsigned long long*)(hb0 + off + 512);
            abuf[1][i * 4 + 2] = ald64(q2);
            abuf[1][i * 4 + 3] = ald64(q2 + 1);
          }
        }
#pragma unroll
        for (int i = 0; i < 4; ++i) {
          const int m = g * 4 + i;
          union { unsigned long long u[2]; bf16x8 v; } a0, a1;
          a0.u[0] = abuf[g][i * 4 + 0]; a0.u[1] = abuf[g][i * 4 + 1];
          a1.u[0] = abuf[g][i * 4 + 2]; a1.u[1] = abuf[g][i * 4 + 3];
          acc00 = MFMA32(a0.v, wf[0][m], acc00);
          acc01 = MFMA32(a0.v, wf[1][m], acc01);
          acc10 = MFMA32(a1.v, wf[0][m], acc10);
          acc11 = MFMA32(a1.v, wf[1][m], acc11);
        }
      }
      if (kw < 2) {  // x-part (ksteps 32/33) from LDS xin
#pragma unroll
        for (int ms = 0; ms < 2; ++ms) {
          const int r = ms * 32 + l31;
          const int gx = kw * 2 + hi5;
          const bf16x8 a = *(const bf16x8*)&xin[r * 40 + ((gx ^ (r & 3)) << 3)];
          if (ms == 0) {
            acc00 = MFMA32(a, wf[0][8], acc00);
            acc01 = MFMA32(a, wf[1][8], acc01);
          } else {
            acc10 = MFMA32(a, wf[0][8], acc10);
            acc11 = MFMA32(a, wf[1][8], acc11);
          }
        }
      }
      PARTS_WRITE(acc00, 0, 0); PARTS_WRITE(acc01, 0, 1);
      PARTS_WRITE(acc10, 1, 0); PARTS_WRITE(acc11, 1, 1);
      __syncthreads();
      cell_update();
      __syncthreads();
      h_publish(region(t & 1, 0, bc));
      relwait();
      __syncthreads();
      if (tid == 0) ast(fslot(0, bc, hc), (unsigned)(t + 2));
    }
    // final prediction y(174) -> out[47]
    if (hc == 0) {
      if (kw == 0 && alive)
        alive = pollw(fslot(1, bc, lane & 31), (unsigned)(kT + 1));
      __syncthreads();
      for (int u = tid; u < 512; u += 256) {
        const int r = u >> 3, o = u & 7;
        out[(size_t)(47 * 512 + b0 + r) * 8 + o] =
            aldf(&yacc[(size_t)(b0 + r) * 8 + o]) + fcb[o];
      }
    }
  } else {
    // =========================== LAYER 1 ===========================
    for (int t = 0; t < kT; ++t) {
      if (kw == 0 && alive) {  // h0(t): >=t+2 ; h1(t-1): >=t+1
        const unsigned* slot = (lane < 32)
            ? fslot(0, bc, lane)
            : fslot(1, bc, lane - 32);
        const unsigned thr = (lane < 32) ? (unsigned)(t + 2) : (unsigned)(t + 1);
        alive = pollw(slot, thr);
      }
      __syncthreads();

      f32x16 acc00 = zero16(), acc01 = zero16(), acc10 = zero16(), acc11 = zero16();
      const char* hbA = region(t & 1, 0, bc);   // h0(t), ksteps 0..31
      const char* hbB = region(t & 1, 1, bc);   // h1(t-1), ksteps 32..63
      unsigned long long abuf[2][16];
#pragma unroll
      for (int i = 0; i < 4; ++i) {  // prefetch group 0
        const char* base = hbA;      // m=0..3 -> jin<32
        const size_t off = (size_t)((2 * (kw + 4 * i) + hi5) * 64 + l31) * 16;
        const unsigned long long* p = (const unsigned long long*)(base + off);
        abuf[0][i * 4 + 0] = ald64(p);
        abuf[0][i * 4 + 1] = ald64(p + 1);
        const unsigned long long* q2 = (const unsigned long long*)(base + off + 512);
        abuf[0][i * 4 + 2] = ald64(q2);
        abuf[0][i * 4 + 3] = ald64(q2 + 1);
      }
#pragma unroll
      for (int g = 0; g < 4; ++g) {
        if (g < 3) {
          const int gn = g + 1;
#pragma unroll
          for (int i = 0; i < 4; ++i) {
            const int m = gn * 4 + i;
            const char* base = (m < 8) ? hbA : hbB;
            const int jl = (kw + 4 * m) & 31;
            const size_t off = (size_t)((2 * jl + hi5) * 64 + l31) * 16;
            const unsigned long long* p = (const unsigned long long*)(base + off);
            abuf[gn & 1][i * 4 + 0] = ald64(p);
            abuf[gn & 1][i * 4 + 1] = ald64(p + 1);
            const unsigned long long* q2 = (const unsigned long long*)(base + off + 512);
            abuf[gn & 1][i * 4 + 2] = ald64(q2);
            abuf[gn & 1][i * 4 + 3] = ald64(q2 + 1);
          }
        }
#pragma unroll
        for (int i = 0; i < 4; ++i) {
          const int m = g * 4 + i;
          union { unsigned long long u[2]; bf16x8 v; } a0, a1;
          a0.u[0] = abuf[g & 1][i * 4 + 0]; a0.u[1] = abuf[g & 1][i * 4 + 1];
          a1.u[0] = abuf[g & 1][i * 4 + 2]; a1.u[1] = abuf[g & 1][i * 4 + 3];
          acc00 = MFMA32(a0.v, wf[0][m], acc00);
          acc01 = MFMA32(a0.v, wf[1][m], acc01);
          acc10 = MFMA32(a1.v, wf[0][m], acc10);
          acc11 = MFMA32(a1.v, wf[1][m], acc11);
        }
      }
      PARTS_WRITE(acc00, 0, 0); PARTS_WRITE(acc01, 0, 1);
      PARTS_WRITE(acc10, 1, 0); PARTS_WRITE(acc11, 1, 1);
      __syncthreads();
      cell_update();
      __syncthreads();
      h_publish(region((t & 1) ^ 1, 1, bc));
      if (t >= kSeq - 1) {  // y(t) partials -> yacc[t&1]
        const int q = t & 1;
#pragma unroll
        for (int rep = 0; rep < 2; ++rep) {
          const int i2 = tid + rep * 256;
          const int r = i2 >> 3, o = i2 & 7;
          float s = 0.0f;
#pragma unroll
          for (int h2 = 0; h2 < 16; ++h2)
            s += bf2f(hloc[r * 24 + h2]) * fcwl[o][h2];
          atomicAdd(&yacc[(size_t)(q * 512 + b0 + r) * 8 + o], s);
        }
      }
      relwait();
      __syncthreads();
      if (tid == 0) ast(fslot(1, bc, hc), (unsigned)(t + 2));
    }
  }
}

extern "C" void kernel_launch(void* const* d_in, const int* in_sizes, int n_in,
                              void* d_out, int out_size, void* d_ws, size_t ws_size,
                              hipStream_t stream) {
  (void)in_sizes; (void)n_in; (void)out_size; (void)ws_size;
  hipMemsetAsync((char*)d_ws + kWsZeroBegin, 0, kWsZeroSize, stream);

  const float* x    = (const float*)d_in[0];
  const float* ft   = (const float*)d_in[1];
  const float* h0in = (const float*)d_in[2];
  const float* c0in = (const float*)d_in[3];
  const float* wih0 = (const float*)d_in[4];
  const float* whh0 = (const float*)d_in[5];
  const float* bih0 = (const float*)d_in[6];
  const float* bhh0 = (const float*)d_in[7];
  const float* wih1 = (const float*)d_in[8];
  const float* whh1 = (const float*)d_in[9];
  const float* bih1 = (const float*)d_in[10];
  const float* bhh1 = (const float*)d_in[11];
  const float* fcw  = (const float*)d_in[12];
  const float* fcb  = (const float*)d_in[13];
  float* out = (float*)d_out;
  char* ws = (char*)d_ws;

  void* args[] = {&x, &ft, &h0in, &c0in, &wih0, &whh0, &bih0, &bhh0,
                  &wih1, &whh1, &bih1, &bhh1, &fcw, &fcb, &out, &ws};
  hipError_t err = hipLaunchCooperativeKernel((void*)lstm_persist, dim3(512),
                                              dim3(256), args, 0, stream);
  if (err != hipSuccess) {
    lstm_persist<<<dim3(512), dim3(256), 0, stream>>>(
        x, ft, h0in, c0in, wih0, whh0, bih0, bhh0,
        wih1, whh1, bih1, bhh1, fcw, fcb, out, ws);
  }
}